// Round 5
// baseline (200.470 us; speedup 1.0000x reference)
//
#include <hip/hip_runtime.h>
#include <hip/hip_bf16.h>

#define B_ 2
#define P_ 100000
#define CIN_ 23
#define C_ 64
#define H_ 512
#define W_ 512
#define S_ (H_*W_)       // 262144
#define NPT_ (B_*P_)     // 200000
#define NVOX_ (B_*S_)    // 524288

typedef __attribute__((ext_vector_type(8))) short short8;
typedef __attribute__((ext_vector_type(4))) float f32x4;

__device__ inline unsigned short f2bf(float f) {
    union { __hip_bfloat16 h; unsigned short u; } cv;
    cv.h = __float2bfloat16(f);
    return cv.u;
}
__device__ inline float bf2f(unsigned short u) {
    union { unsigned int i; float f; } cv;
    cv.i = ((unsigned int)u) << 16;
    return cv.f;
}

// ---------------- Stage 1: lists + compact occupied-voxel worklist ----------------
__global__ __launch_bounds__(256) void k_fill(
    const int* __restrict__ indices,
    const int* __restrict__ paddings,
    int* __restrict__ head,
    int* __restrict__ next,
    int* __restrict__ wl,
    int* __restrict__ cnt)
{
    int pt = blockIdx.x * 256 + threadIdx.x;
    if (pt >= NPT_) return;
    if (paddings[pt] != 0) return;              // padded -> dropped
    int v = (pt / P_) * S_ + indices[pt];
    int old = atomicExch(&head[v], pt);
    next[pt] = old;
    if (old < 0) {                              // first toucher appends voxel
        int slot = atomicAdd(cnt, 1);
        wl[slot] = v;
    }
}

// ---------------- Stage 2: PointNet + max over occupied voxels ----------------
// 4 voxels per wave (4 independent walk chains), lane = channel
__global__ __launch_bounds__(256) void k_pn_occ(
    const float* __restrict__ feat,
    const int* __restrict__ head,
    const int* __restrict__ next,
    const int* __restrict__ wl,
    const float* __restrict__ w_pn,
    const float* __restrict__ bg, const float* __restrict__ bb,
    const float* __restrict__ bm, const float* __restrict__ bv,
    unsigned short* __restrict__ grid)          // bf16 [NVOX_][C_]
{
    int lane = threadIdx.x & 63;
    int wid  = (blockIdx.x * 256 + threadIdx.x) >> 6;
    int e0   = wid * 4;
    if (e0 >= NPT_) return;

    int va = wl[e0];
    if (va < 0) return;                         // -1s contiguous at tail
    int vb = wl[e0 + 1], vc = wl[e0 + 2], vd = wl[e0 + 3];

    float w[CIN_];
    #pragma unroll
    for (int i = 0; i < CIN_; ++i) w[i] = w_pn[i * C_ + lane];

    int pa = head[va];
    int pb = vb >= 0 ? head[vb] : -1;
    int pc = vc >= 0 ? head[vc] : -1;
    int pd = vd >= 0 ? head[vd] : -1;

    float mxa = -1e30f, mxb = -1e30f, mxc = -1e30f, mxd = -1e30f;
    while (pa >= 0 || pb >= 0 || pc >= 0 || pd >= 0) {
        const float* fa = feat + (size_t)(pa < 0 ? 0 : pa) * CIN_;
        const float* fb = feat + (size_t)(pb < 0 ? 0 : pb) * CIN_;
        const float* fc = feat + (size_t)(pc < 0 ? 0 : pc) * CIN_;
        const float* fd = feat + (size_t)(pd < 0 ? 0 : pd) * CIN_;
        int na = pa < 0 ? -1 : next[pa];
        int nb = pb < 0 ? -1 : next[pb];
        int nc = pc < 0 ? -1 : next[pc];
        int nd = pd < 0 ? -1 : next[pd];
        float aa = 0.f, ab = 0.f, ac = 0.f, ad = 0.f;
        #pragma unroll
        for (int i = 0; i < CIN_; ++i) {
            aa += fa[i] * w[i];
            ab += fb[i] * w[i];
            ac += fc[i] * w[i];
            ad += fd[i] * w[i];
        }
        if (pa >= 0) mxa = fmaxf(mxa, aa);
        if (pb >= 0) mxb = fmaxf(mxb, ab);
        if (pc >= 0) mxc = fmaxf(mxc, ac);
        if (pd >= 0) mxd = fmaxf(mxd, ad);
        pa = pa < 0 ? pa : na;
        pb = pb < 0 ? pb : nb;
        pc = pc < 0 ? pc : nc;
        pd = pd < 0 ? pd : nd;
    }

    float s   = bg[lane] * rsqrtf(bv[lane] + 1e-5f);
    float off = bb[lane] - bm[lane] * s;
    grid[(size_t)va * C_ + lane] = f2bf(fmaxf(mxa * s + off, 0.f));
    if (vb >= 0) grid[(size_t)vb * C_ + lane] = f2bf(fmaxf(mxb * s + off, 0.f));
    if (vc >= 0) grid[(size_t)vc * C_ + lane] = f2bf(fmaxf(mxc * s + off, 0.f));
    if (vd >= 0) grid[(size_t)vd * C_ + lane] = f2bf(fmaxf(mxd * s + off, 0.f));
}

// ---------------- Stage 3: 1x1 conv + BN2 + ReLU over occupied rows only ----------------
__global__ __launch_bounds__(256) void k_conv_occ(
    unsigned short* __restrict__ grid,      // bf16
    const int* __restrict__ wl,
    const float* __restrict__ conv_w,       // [out n][in k] f32
    const float* __restrict__ g2, const float* __restrict__ b2,
    const float* __restrict__ m2, const float* __restrict__ v2)
{
    int lane = threadIdx.x & 63;
    int wid  = (blockIdx.x * 256 + threadIdx.x) >> 6;
    int e0   = wid * 16;
    if (e0 >= NPT_) return;
    if (wl[e0] < 0) return;                 // whole tile past tail

    int row = lane & 15;
    int grp = lane >> 4;

    int vidr  = wl[e0 + row];
    int vsafe = vidr < 0 ? 0 : vidr;

    short8 bfrag[4][2];
    #pragma unroll
    for (int t = 0; t < 4; ++t)
        #pragma unroll
        for (int ks = 0; ks < 2; ++ks) {
            const float* wp = conv_w + (t * 16 + row) * 64 + ks * 32 + grp * 8;
            f32x4 lo = *(const f32x4*)(wp);
            f32x4 hi = *(const f32x4*)(wp + 4);
            short8 vv;
            #pragma unroll
            for (int j = 0; j < 4; ++j) {
                vv[j]     = (short)f2bf(lo[j]);
                vv[j + 4] = (short)f2bf(hi[j]);
            }
            bfrag[t][ks] = vv;
        }

    float sc[4], sh[4];
    #pragma unroll
    for (int t = 0; t < 4; ++t) {
        int n   = t * 16 + row;
        float s = g2[n] * rsqrtf(v2[n] + 1e-3f);
        sc[t] = s;
        sh[t] = b2[n] - m2[n] * s;
    }

    const unsigned short* ap = grid + (size_t)vsafe * C_;
    short8 a[2];
    #pragma unroll
    for (int ks = 0; ks < 2; ++ks)
        a[ks] = *(const short8*)(ap + ks * 32 + grp * 8);

    f32x4 acc[4];
    #pragma unroll
    for (int t = 0; t < 4; ++t) acc[t] = (f32x4){0.f, 0.f, 0.f, 0.f};
    #pragma unroll
    for (int t = 0; t < 4; ++t) {
        acc[t] = __builtin_amdgcn_mfma_f32_16x16x32_bf16(a[0], bfrag[t][0], acc[t], 0, 0, 0);
        acc[t] = __builtin_amdgcn_mfma_f32_16x16x32_bf16(a[1], bfrag[t][1], acc[t], 0, 0, 0);
    }

    #pragma unroll
    for (int r = 0; r < 4; ++r) {
        int vm = wl[e0 + grp * 4 + r];
        if (vm < 0) continue;
        unsigned short* op = grid + (size_t)vm * C_;
        #pragma unroll
        for (int t = 0; t < 4; ++t) {
            float val = fmaxf(acc[t][r] * sc[t] + sh[t], 0.f);
            op[t * 16 + row] = f2bf(val);
        }
    }
}

// ---------------- Stage 4: bilinear gather with empty-voxel constant ----------------
__global__ __launch_bounds__(256) void k_gather(
    const unsigned short* __restrict__ grid,
    const int* __restrict__ head,
    const float* __restrict__ vxyz,
    const float* __restrict__ g2, const float* __restrict__ b2,
    const float* __restrict__ m2, const float* __restrict__ v2,
    float* __restrict__ out)
{
    int t  = blockIdx.x * 256 + threadIdx.x;
    int c  = t & 63;
    int pt = t >> 6;
    if (pt >= NPT_) return;
    int b = pt / P_;

    float s2  = g2[c] * rsqrtf(v2[c] + 1e-3f);
    float cst = fmaxf(b2[c] - m2[c] * s2, 0.f);   // conv(0)+BN2+ReLU

    float xq = vxyz[(size_t)pt * 3 + 0];
    float yq = vxyz[(size_t)pt * 3 + 1];
    int x0 = (int)floorf(xq); x0 = min(max(x0, 0), W_ - 1);
    int x1 = min(x0 + 1, W_ - 1);
    int y0 = (int)floorf(yq); y0 = min(max(y0, 0), H_ - 1);
    int y1 = min(y0 + 1, H_ - 1);
    float x0f = (float)x0, x1f = (float)x1, y0f = (float)y0, y1f = (float)y1;
    float wa = (x1f - xq) * (y1f - yq);
    float wb = (x1f - xq) * (yq - y0f);
    float wc = (xq - x0f) * (y1f - yq);
    float wd = (xq - x0f) * (yq - y0f);

    int ia = y0 * W_ + x0, ib = y1 * W_ + x0, ic = y0 * W_ + x1, id = y1 * W_ + x1;
    const int* hb = head + (size_t)b * S_;
    const unsigned short* g = grid + (size_t)b * S_ * C_;
    float Ia = hb[ia] >= 0 ? bf2f(g[(size_t)ia * C_ + c]) : cst;
    float Ib = hb[ib] >= 0 ? bf2f(g[(size_t)ib * C_ + c]) : cst;
    float Ic = hb[ic] >= 0 ? bf2f(g[(size_t)ic * C_ + c]) : cst;
    float Id = hb[id] >= 0 ? bf2f(g[(size_t)id * C_ + c]) : cst;

    out[t] = wa * Ia + wb * Ib + wc * Ic + wd * Id;
}

extern "C" void kernel_launch(void* const* d_in, const int* in_sizes, int n_in,
                              void* d_out, int out_size, void* d_ws, size_t ws_size,
                              hipStream_t stream)
{
    const float* feat     = (const float*)d_in[1];
    const int*   indices  = (const int*)d_in[3];
    const int*   paddings = (const int*)d_in[4];
    const float* vxyz     = (const float*)d_in[5];
    const float* w_pn     = (const float*)d_in[6];
    const float* g1       = (const float*)d_in[7];
    const float* b1       = (const float*)d_in[8];
    const float* m1       = (const float*)d_in[9];
    const float* v1       = (const float*)d_in[10];
    const float* cw       = (const float*)d_in[11];
    const float* g2       = (const float*)d_in[12];
    const float* b2       = (const float*)d_in[13];
    const float* m2       = (const float*)d_in[14];
    const float* v2       = (const float*)d_in[15];

    // ws layout: grid bf16 67.1MB | head 2.1MB | wl 0.8MB | next 0.8MB | cnt 4B
    unsigned short* grid = (unsigned short*)d_ws;
    char* base = (char*)d_ws + (size_t)NVOX_ * C_ * sizeof(unsigned short);
    int* head = (int*)base;
    int* wl   = head + NVOX_;
    int* next = wl + NPT_;
    int* cnt  = next + NPT_;

    hipMemsetAsync(head, 0xFF, (size_t)(NVOX_ + NPT_) * sizeof(int), stream); // head+wl = -1
    hipMemsetAsync(cnt, 0, sizeof(int), stream);

    k_fill<<<(NPT_ + 255) / 256, 256, 0, stream>>>(indices, paddings, head, next, wl, cnt);

    // ceil(NPT_/4)=50000 waves -> 12500 blocks
    k_pn_occ<<<12500, 256, 0, stream>>>(feat, head, next, wl, w_pn, g1, b1, m1, v1, grid);

    // ceil(NPT_/16)=12500 waves -> 3125 blocks
    k_conv_occ<<<3125, 256, 0, stream>>>(grid, wl, cw, g2, b2, m2, v2);

    k_gather<<<(NPT_ * C_) / 256, 256, 0, stream>>>(
        grid, head, vxyz, g2, b2, m2, v2, (float*)d_out);
}